// Round 6
// baseline (485.775 us; speedup 1.0000x reference)
//
#include <hip/hip_runtime.h>
#include <hip/hip_bf16.h>
#include <math.h>

// NoisyTopkRouter: rows=32768, D=4096, E=64, k=8.
// R6: barrier-free, LDS-free main loop. W planes precomputed to d_ws (L2-hot,
// fragment-ready layout) and read straight into MFMA B-frags; h prefetched
// global->reg (2-step ping-pong), split3 in-register at consume time.
// BM=32, 1024 blocks, 4 waves (1x4 grid), 3 waves/SIMD target.
// Output (fp32): gates[rows*64] | ix[rows*8] | full[rows*64]

typedef __attribute__((ext_vector_type(8))) short bf16x8;
typedef __attribute__((ext_vector_type(4))) float f32x4;
typedef unsigned int u32;

#define BM 32
#define D_DIM 4096
#define NSTEP 128
#define WSTEP_BYTES 24576   // per-step W image: 3 planes x 8KB

__device__ __forceinline__ float softplus_f(float x) {
    return fmaxf(x, 0.0f) + log1pf(expf(-fabsf(x)));
}

// Exact 3-way truncation split: x == f(u0)+f(u1)+f(u2), each bf16-representable.
__device__ __forceinline__ void split3(float x, u32 &u0, u32 &u1, u32 &u2) {
    u32 ux = __float_as_uint(x);
    u0 = ux & 0xffff0000u;
    float r = x - __uint_as_float(u0);
    u32 ur = __float_as_uint(r);
    u1 = ur & 0xffff0000u;
    float r2 = r - __uint_as_float(u1);
    u2 = __float_as_uint(r2);      // low 16 bits zero by construction
}

// ---- W pre-conversion: 3 bf16 planes, per-step 24KB fragment-ready image ----
// image[kc][p*8192 + vrow*64 + sc*16], sc = c4 ^ ((vrow>>2)&3)
__global__ __launch_bounds__(256)
void wconv_kernel(const float* __restrict__ Ww, const float* __restrict__ Wn,
                  char* __restrict__ Wp)
{
    const int bid = blockIdx.x;            // 256 blocks
    const int kc = bid >> 1, half = bid & 1;
    const int t = threadIdx.x;
    const int vrow = half * 64 + (t >> 2); // 0..127 (0-63=Ww, 64-127=Wn)
    const int c4 = t & 3;                  // 16B chunk (8 k-elements)
    const float* src = (vrow < 64) ? (Ww + (size_t)vrow * D_DIM)
                                   : (Wn + (size_t)(vrow - 64) * D_DIM);
    const float4 a = *reinterpret_cast<const float4*>(src + kc * 32 + c4 * 8);
    const float4 b = *reinterpret_cast<const float4*>(src + kc * 32 + c4 * 8 + 4);
    const float f[8] = {a.x, a.y, a.z, a.w, b.x, b.y, b.z, b.w};
    u32 p0[4], p1[4], p2[4];
#pragma unroll
    for (int i = 0; i < 4; ++i) {
        u32 x0, x1, x2, y0, y1, y2;
        split3(f[2 * i], x0, x1, x2);
        split3(f[2 * i + 1], y0, y1, y2);
        p0[i] = y0 | (x0 >> 16);
        p1[i] = y1 | (x1 >> 16);
        p2[i] = (y2 & 0xffff0000u) | (x2 >> 16);
    }
    const int sc = c4 ^ ((vrow >> 2) & 3);
    char* dst = Wp + (size_t)kc * WSTEP_BYTES + vrow * 64 + sc * 16;
    *reinterpret_cast<uint4*>(dst)          = make_uint4(p0[0], p0[1], p0[2], p0[3]);
    *reinterpret_cast<uint4*>(dst + 8192)   = make_uint4(p1[0], p1[1], p1[2], p1[3]);
    *reinterpret_cast<uint4*>(dst + 16384)  = make_uint4(p2[0], p2[1], p2[2], p2[3]);
}

#define MFMA16(A, B, C) __builtin_amdgcn_mfma_f32_16x16x32_bf16((A), (B), (C), 0, 0, 0)

// One K-step: split staged h regs -> A frags, reload the reg set for KC+2,
// load B frags from L2-hot Wp, 24 MFMA.
#define STEP(KC, R0, R1, R2, R3)                                              \
    {                                                                         \
        bf16x8 A0[2], A1[2], A2[2];                                           \
        {                                                                     \
            const float f0[8] = {R0.x, R0.y, R0.z, R0.w, R1.x, R1.y, R1.z, R1.w}; \
            const float f1[8] = {R2.x, R2.y, R2.z, R2.w, R3.x, R3.y, R3.z, R3.w}; \
            union { u32 u[4]; bf16x8 v; } q0, q1, q2, s0, s1, s2;             \
            _Pragma("unroll")                                                 \
            for (int i = 0; i < 4; ++i) {                                     \
                u32 x0, x1, x2, y0, y1, y2;                                   \
                split3(f0[2 * i], x0, x1, x2);                                \
                split3(f0[2 * i + 1], y0, y1, y2);                            \
                q0.u[i] = y0 | (x0 >> 16);                                    \
                q1.u[i] = y1 | (x1 >> 16);                                    \
                q2.u[i] = (y2 & 0xffff0000u) | (x2 >> 16);                    \
                split3(f1[2 * i], x0, x1, x2);                                \
                split3(f1[2 * i + 1], y0, y1, y2);                            \
                s0.u[i] = y0 | (x0 >> 16);                                    \
                s1.u[i] = y1 | (x1 >> 16);                                    \
                s2.u[i] = (y2 & 0xffff0000u) | (x2 >> 16);                    \
            }                                                                 \
            A0[0] = q0.v; A1[0] = q1.v; A2[0] = q2.v;                         \
            A0[1] = s0.v; A1[1] = s1.v; A2[1] = s2.v;                         \
        }                                                                     \
        {   /* reload this reg set for step KC+2 (clamped; redundant at tail) */ \
            const int kn = ((KC) + 2 < NSTEP) ? ((KC) + 2) : (NSTEP - 1);     \
            R0 = *reinterpret_cast<const float4*>(hp0 + kn * 32);             \
            R1 = *reinterpret_cast<const float4*>(hp0 + kn * 32 + 4);         \
            R2 = *reinterpret_cast<const float4*>(hp1 + kn * 32);             \
            R3 = *reinterpret_cast<const float4*>(hp1 + kn * 32 + 4);         \
        }                                                                     \
        const char* bstep = bp + (size_t)(KC) * WSTEP_BYTES;                  \
        _Pragma("unroll")                                                     \
        for (int j = 0; j < 2; ++j) {                                         \
            const bf16x8 Bb0 = *reinterpret_cast<const bf16x8*>(bstep + j * 1024);         \
            const bf16x8 Bb1 = *reinterpret_cast<const bf16x8*>(bstep + j * 1024 + 8192);  \
            const bf16x8 Bb2 = *reinterpret_cast<const bf16x8*>(bstep + j * 1024 + 16384); \
            _Pragma("unroll")                                                 \
            for (int fi = 0; fi < 2; ++fi) {                                  \
                grp[fi][j]  = MFMA16(A0[fi], Bb0, grp[fi][j]);                \
                accB[fi][j] = MFMA16(A0[fi], Bb1, accB[fi][j]);               \
                accB[fi][j] = MFMA16(A1[fi], Bb0, accB[fi][j]);               \
                accB[fi][j] = MFMA16(A1[fi], Bb1, accB[fi][j]);               \
                accB[fi][j] = MFMA16(A0[fi], Bb2, accB[fi][j]);               \
                accB[fi][j] = MFMA16(A2[fi], Bb0, accB[fi][j]);               \
            }                                                                 \
        }                                                                     \
    }

__global__ __launch_bounds__(256, 3)
void router_kernel(const float* __restrict__ h,
                   const float* __restrict__ bw,
                   const float* __restrict__ bn,
                   const float* __restrict__ noise,
                   const char* __restrict__ Wp,
                   float* __restrict__ out_gates,
                   float* __restrict__ out_ix,
                   float* __restrict__ out_full)
{
    __shared__ __align__(16) float lds[2 * 32 * 65];   // epilogue only, 16.6KB

    const int t = threadIdx.x;
    const int lane = t & 63, w = t >> 6;
    const int c = lane & 15, kg = lane >> 4;
    const int row0 = blockIdx.x * BM;

    // per-lane global bases
    const float* hp0 = h + (size_t)(row0 + c) * D_DIM + kg * 8;        // fi=0 rows
    const float* hp1 = h + (size_t)(row0 + 16 + c) * D_DIM + kg * 8;   // fi=1 rows
    const char*  bp  = Wp + (w * 32 + c) * 64 + ((kg ^ ((c >> 2) & 3)) * 16);

    f32x4 grp[2][2], sA[2][2], cA[2][2], accB[2][2];
#pragma unroll
    for (int fi = 0; fi < 2; ++fi)
#pragma unroll
        for (int j = 0; j < 2; ++j) {
            grp[fi][j] = (f32x4)0.0f; sA[fi][j] = (f32x4)0.0f;
            cA[fi][j]  = (f32x4)0.0f; accB[fi][j] = (f32x4)0.0f;
        }

    // prologue: prefetch steps 0 (set A) and 1 (set B) into registers
    float4 a0 = *reinterpret_cast<const float4*>(hp0);
    float4 a1 = *reinterpret_cast<const float4*>(hp0 + 4);
    float4 a2 = *reinterpret_cast<const float4*>(hp1);
    float4 a3 = *reinterpret_cast<const float4*>(hp1 + 4);
    float4 b0 = *reinterpret_cast<const float4*>(hp0 + 32);
    float4 b1 = *reinterpret_cast<const float4*>(hp0 + 36);
    float4 b2 = *reinterpret_cast<const float4*>(hp1 + 32);
    float4 b3 = *reinterpret_cast<const float4*>(hp1 + 36);

    for (int kc = 0; kc < NSTEP; kc += 2) {
        STEP(kc, a0, a1, a2, a3);
        STEP(kc + 1, b0, b1, b2, b3);
        if (((kc + 1) & 7) == 7) {   // Kahan fold every 8 steps
#pragma unroll
            for (int fi = 0; fi < 2; ++fi)
#pragma unroll
                for (int j = 0; j < 2; ++j) {
#pragma unroll
                    for (int e = 0; e < 4; ++e) {
                        float y  = grp[fi][j][e] - cA[fi][j][e];
                        float tt = sA[fi][j][e] + y;
                        cA[fi][j][e] = (tt - sA[fi][j][e]) - y;
                        sA[fi][j][e] = tt;
                    }
                    grp[fi][j] = (f32x4)0.0f;
                }
        }
    }

    // ---- logits -> LDS ----
    // C/D layout: col = lane&15, row = (lane>>4)*4 + reg
    float* lw_s = lds;             // [32][65]
    float* ln_s = lds + 32 * 65;   // [32][65]
    float* dst = (w < 2) ? lw_s : ln_s;
    const int ebase = (w & 1) * 32;
#pragma unroll
    for (int fi = 0; fi < 2; ++fi)
#pragma unroll
        for (int j = 0; j < 2; ++j)
#pragma unroll
            for (int r = 0; r < 4; ++r) {
                const int rowl = fi * 16 + kg * 4 + r;
                const int e = ebase + j * 16 + c;
                dst[rowl * 65 + e] = sA[fi][j][r] + accB[fi][j][r];
            }
    __syncthreads();

    // ---- noisy + top-8 + softmaxes: wave w -> rows w*8..w*8+7, lane = expert ----
    const float bwv = bw[lane];
    const float bnv = bn[lane];
    for (int q = 0; q < 8; ++q) {
        const int lrow = w * 8 + q;
        const int grow = row0 + lrow;
        const float lwv = lw_s[lrow * 65 + lane] + bwv;
        const float lnv = ln_s[lrow * 65 + lane] + bnv;
        const float nz  = noise[(size_t)grow * 64 + lane];
        const float v   = lwv + nz * softplus_f(lnv);

        float cur2 = v;
        float m8 = 0.0f;
        int winIdx = 0;
        bool picked = false;
#pragma unroll
        for (int r = 0; r < 8; ++r) {
            float bvv = cur2;
            int   bi  = lane;
#pragma unroll
            for (int off = 32; off; off >>= 1) {
                const float ov = __shfl_xor(bvv, off);
                const int   oi = __shfl_xor(bi, off);
                if (ov > bvv || (ov == bvv && oi < bi)) { bvv = ov; bi = oi; }
            }
            if (r == 0) m8 = bvv;
            if (lane == r) winIdx = bi;
            if (lane == bi) { picked = true; cur2 = -INFINITY; }
        }

        const float pf = expf(v - m8);
        const float pg = picked ? pf : 0.0f;
        float sf = pf, sg = pg;
#pragma unroll
        for (int off = 32; off; off >>= 1) {
            sf += __shfl_xor(sf, off);
            sg += __shfl_xor(sg, off);
        }

        out_full [(size_t)grow * 64 + lane] = pf / sf;
        out_gates[(size_t)grow * 64 + lane] = pg / sg;
        if (lane < 8) out_ix[(size_t)grow * 8 + lane] = (float)winIdx;
    }
}

extern "C" void kernel_launch(void* const* d_in, const int* in_sizes, int n_in,
                              void* d_out, int out_size, void* d_ws, size_t ws_size,
                              hipStream_t stream) {
    const float* h  = (const float*)d_in[0];
    const float* Ww = (const float*)d_in[1];
    const float* bw = (const float*)d_in[2];
    const float* Wn = (const float*)d_in[3];
    const float* bn = (const float*)d_in[4];
    const float* nz = (const float*)d_in[5];

    const int rows = in_sizes[5] / 64;   // 32768

    float* out = (float*)d_out;
    float* og = out;
    float* oi = out + (size_t)rows * 64;
    float* of = out + (size_t)rows * 64 + (size_t)rows * 8;

    char* Wp = (char*)d_ws;   // 128 steps * 24576 B = 3 MB

    hipLaunchKernelGGL(wconv_kernel, dim3(256), dim3(256), 0, stream, Ww, Wn, Wp);
    hipLaunchKernelGGL(router_kernel, dim3(rows / BM), dim3(256), 0, stream,
                       h, bw, bn, nz, Wp, og, oi, of);
}

// Round 7
// 249.701 us; speedup vs baseline: 1.9454x; 1.9454x over previous
//
#include <hip/hip_runtime.h>
#include <hip/hip_bf16.h>
#include <math.h>

// NoisyTopkRouter: rows=32768, D=4096, E=64, k=8.
// R7: R5 staging skeleton (gl16 -> LDS double-buffer) + fp16x2 exact-ish split
// (4 MFMA/tile: main, mid@2^11, hi@2^22), 512-thread blocks (8 waves, 2x4),
// W 2-plane image precomputed in d_ws, fold-16 group accumulation.
// Output (fp32): gates[rows*64] | ix[rows*8] | full[rows*64]

typedef __attribute__((ext_vector_type(8))) _Float16 f16x8;
typedef __attribute__((ext_vector_type(4))) float f32x4;
typedef unsigned int u32;

#define BM 64
#define D_DIM 4096
#define NSTEP 128
#define WSTEP_BYTES 16384      // per-step W image: 2 planes x 8KB

// LDS per buffer: h 8KB + W 16KB = 24KB; double-buffered = 48KB
#define BUF_BYTES 24576
#define SMEM_BYTES 49152

__device__ __forceinline__ float softplus_f(float x) {
    return fmaxf(x, 0.0f) + log1pf(expf(-fabsf(x)));
}

__device__ __forceinline__ void gl16(void* lds, const void* g) {
    __builtin_amdgcn_global_load_lds(
        (const __attribute__((address_space(1))) u32*)g,
        (__attribute__((address_space(3))) u32*)lds, 16, 0, 0);
}

#define MFMA16F(A, B, C) __builtin_amdgcn_mfma_f32_16x16x32_f16((A), (B), (C), 0, 0, 0)

// ---- W pre-conversion: 2 fp16 planes (p0 = f16(w), p1 = f16((w-p0)*2048)),
// per-step 16KB fragment-ready image, chunk-swizzled: sc = c4 ^ ((vrow>>2)&3)
__global__ __launch_bounds__(256)
void wconv_kernel(const float* __restrict__ Ww, const float* __restrict__ Wn,
                  char* __restrict__ Wp)
{
    const int bid = blockIdx.x;            // 256 blocks
    const int kc = bid >> 1, half = bid & 1;
    const int t = threadIdx.x;
    const int vrow = half * 64 + (t >> 2); // 0..127 (0-63=Ww, 64-127=Wn)
    const int c4 = t & 3;                  // 16B chunk (8 fp32 k-elements -> 8 fp16)
    const float* src = (vrow < 64) ? (Ww + (size_t)vrow * D_DIM)
                                   : (Wn + (size_t)(vrow - 64) * D_DIM);
    const float4 a = *reinterpret_cast<const float4*>(src + kc * 32 + c4 * 8);
    const float4 b = *reinterpret_cast<const float4*>(src + kc * 32 + c4 * 8 + 4);
    const float f[8] = {a.x, a.y, a.z, a.w, b.x, b.y, b.z, b.w};
    union { _Float16 h[8]; uint4 q; } P0, P1;
#pragma unroll
    for (int i = 0; i < 8; ++i) {
        _Float16 lo = (_Float16)f[i];
        P0.h[i] = lo;
        P1.h[i] = (_Float16)((f[i] - (float)lo) * 2048.0f);
    }
    const int sc = c4 ^ ((vrow >> 2) & 3);
    char* dst = Wp + (size_t)kc * WSTEP_BYTES + vrow * 64 + sc * 16;
    *reinterpret_cast<uint4*>(dst)        = P0.q;
    *reinterpret_cast<uint4*>(dst + 8192) = P1.q;
}

__global__ __launch_bounds__(512, 4)
void router_kernel(const float* __restrict__ h,
                   const float* __restrict__ bw,
                   const float* __restrict__ bn,
                   const float* __restrict__ noise,
                   const char* __restrict__ Wp,
                   float* __restrict__ out_gates,
                   float* __restrict__ out_ix,
                   float* __restrict__ out_full)
{
    __shared__ __align__(16) char smem[SMEM_BYTES];

    const int t    = threadIdx.x;
    const int row0 = blockIdx.x * BM;
    const int lane = t & 63, w = t >> 6;        // 8 waves
    const int c = lane & 15, kg = lane >> 4;
    const int wr = w >> 2, wc = w & 3;          // 2x4 grid: rows wr*32.., vcols wc*32..

    // ---- staging geometry ----
    // h image[row*128 + sc*16] (raw fp32, sc = chunk ^ (row&7)): 1 gl16/thread
    const int hl  = lane >> 3;                  // row-within-8
    const int hsc = (lane & 7) ^ hl;            // pre-swizzled source chunk
    const float* hsrc = h + (size_t)(row0 + w * 8 + hl) * D_DIM + hsc * 4;
    const int hdst = w * 1024;                  // wave-uniform LDS base (+ lane*16 by DMA)
    // W image: 2 gl16/thread (linear copy, swizzle baked into image)
    const char* wsrc = Wp + w * 1024 + lane * 16;

    // ---- accumulators: grp (fold-16 main), sA, accM (@2^11), accM2 (@2^22) ----
    f32x4 grp[2][2], sA[2][2], accM[2][2], accM2[2][2];
#pragma unroll
    for (int fi = 0; fi < 2; ++fi)
#pragma unroll
        for (int j = 0; j < 2; ++j) {
            grp[fi][j] = (f32x4)0.0f; sA[fi][j] = (f32x4)0.0f;
            accM[fi][j] = (f32x4)0.0f; accM2[fi][j] = (f32x4)0.0f;
        }

    // prologue: stage step 0 into buf 0
    gl16(smem + hdst, hsrc);
    gl16(smem + 8192 + w * 1024, wsrc);
    gl16(smem + 8192 + 8192 + w * 1024, wsrc + 8192);
    __syncthreads();

    int cur = 0;
    for (int kc = 0; kc < NSTEP; ++kc) {
        // stage next step into other buffer (in flight across this step's compute)
        if (kc + 1 < NSTEP) {
            char* nb = smem + (cur ^ 1) * BUF_BYTES;
            gl16(nb + hdst, hsrc + (size_t)(kc + 1) * 32);
            const char* ws = wsrc + (size_t)(kc + 1) * WSTEP_BYTES;
            gl16(nb + 8192 + w * 1024, ws);
            gl16(nb + 16384 + w * 1024, ws + 8192);
        }

        const char* hb = smem + cur * BUF_BYTES;
        const char* wb = hb + 8192;

        // ---- A fragments: read raw fp32 h, fp16x2 split in-register ----
        f16x8 A0[2], A1[2];
#pragma unroll
        for (int fi = 0; fi < 2; ++fi) {
            const int arow = wr * 32 + fi * 16 + c;
            const int s0 = ((kg * 2)     ^ (arow & 7)) * 16;
            const int s1 = ((kg * 2 + 1) ^ (arow & 7)) * 16;
            const float4 fa = *reinterpret_cast<const float4*>(hb + arow * 128 + s0);
            const float4 fb = *reinterpret_cast<const float4*>(hb + arow * 128 + s1);
            const float f[8] = {fa.x, fa.y, fa.z, fa.w, fb.x, fb.y, fb.z, fb.w};
#pragma unroll
            for (int i = 0; i < 8; ++i) {
                _Float16 lo = (_Float16)f[i];
                A0[fi][i] = lo;
                A1[fi][i] = (_Float16)((f[i] - (float)lo) * 2048.0f);
            }
        }

        // ---- B fragments + 4-term MFMA ----
#pragma unroll
        for (int j = 0; j < 2; ++j) {
            const int brow = wc * 32 + j * 16 + c;
            const int bo = brow * 64 + ((kg ^ ((brow >> 2) & 3)) * 16);
            const f16x8 B0 = *reinterpret_cast<const f16x8*>(wb + bo);
            const f16x8 B1 = *reinterpret_cast<const f16x8*>(wb + bo + 8192);
#pragma unroll
            for (int fi = 0; fi < 2; ++fi) {
                grp[fi][j]   = MFMA16F(A0[fi], B0, grp[fi][j]);
                accM[fi][j]  = MFMA16F(A0[fi], B1, accM[fi][j]);
                accM[fi][j]  = MFMA16F(A1[fi], B0, accM[fi][j]);
                accM2[fi][j] = MFMA16F(A1[fi], B1, accM2[fi][j]);
            }
        }

        // fold group into sA every 16 steps (last fold at kc=127)
        if ((kc & 15) == 15) {
#pragma unroll
            for (int fi = 0; fi < 2; ++fi)
#pragma unroll
                for (int j = 0; j < 2; ++j) {
#pragma unroll
                    for (int e = 0; e < 4; ++e) sA[fi][j][e] += grp[fi][j][e];
                    grp[fi][j] = (f32x4)0.0f;
                }
        }

        __syncthreads();   // next buffer staged, this buffer free
        cur ^= 1;
    }

    // ---- logits -> LDS ----
    // C/D layout: col = lane&15, row = (lane>>4)*4 + reg
    float* lw_s = reinterpret_cast<float*>(smem);            // [64][65]
    float* ln_s = lw_s + 64 * 65;                            // [64][65]
    float* dst = (wc < 2) ? lw_s : ln_s;
#pragma unroll
    for (int fi = 0; fi < 2; ++fi)
#pragma unroll
        for (int j = 0; j < 2; ++j)
#pragma unroll
            for (int r = 0; r < 4; ++r) {
                const int rowl = wr * 32 + fi * 16 + kg * 4 + r;
                const int e = (wc & 1) * 32 + j * 16 + c;
                dst[rowl * 65 + e] = sA[fi][j][r]
                                   + accM[fi][j][r]  * 4.8828125e-4f      // 2^-11
                                   + accM2[fi][j][r] * 2.384185791015625e-7f; // 2^-22
            }
    __syncthreads();

    // ---- noisy + top-8 + softmaxes: wave w -> rows w*8..w*8+7, lane = expert ----
    const float bwv = bw[lane];
    const float bnv = bn[lane];
    for (int q = 0; q < 8; ++q) {
        const int lrow = w * 8 + q;
        const int grow = row0 + lrow;
        const float lwv = lw_s[lrow * 65 + lane] + bwv;
        const float lnv = ln_s[lrow * 65 + lane] + bnv;
        const float nz  = noise[(size_t)grow * 64 + lane];
        const float v   = lwv + nz * softplus_f(lnv);

        float cur2 = v;
        float m8 = 0.0f;
        int winIdx = 0;
        bool picked = false;
#pragma unroll
        for (int r = 0; r < 8; ++r) {
            float bvv = cur2;
            int   bi  = lane;
#pragma unroll
            for (int off = 32; off; off >>= 1) {
                const float ov = __shfl_xor(bvv, off);
                const int   oi = __shfl_xor(bi, off);
                if (ov > bvv || (ov == bvv && oi < bi)) { bvv = ov; bi = oi; }
            }
            if (r == 0) m8 = bvv;
            if (lane == r) winIdx = bi;
            if (lane == bi) { picked = true; cur2 = -INFINITY; }
        }

        const float pf = expf(v - m8);
        const float pg = picked ? pf : 0.0f;
        float sf = pf, sg = pg;
#pragma unroll
        for (int off = 32; off; off >>= 1) {
            sf += __shfl_xor(sf, off);
            sg += __shfl_xor(sg, off);
        }

        out_full [(size_t)grow * 64 + lane] = pf / sf;
        out_gates[(size_t)grow * 64 + lane] = pg / sg;
        if (lane < 8) out_ix[(size_t)grow * 8 + lane] = (float)winIdx;
    }
}

extern "C" void kernel_launch(void* const* d_in, const int* in_sizes, int n_in,
                              void* d_out, int out_size, void* d_ws, size_t ws_size,
                              hipStream_t stream) {
    const float* h  = (const float*)d_in[0];
    const float* Ww = (const float*)d_in[1];
    const float* bw = (const float*)d_in[2];
    const float* Wn = (const float*)d_in[3];
    const float* bn = (const float*)d_in[4];
    const float* nz = (const float*)d_in[5];

    const int rows = in_sizes[5] / 64;   // 32768

    float* out = (float*)d_out;
    float* og = out;
    float* oi = out + (size_t)rows * 64;
    float* of = out + (size_t)rows * 64 + (size_t)rows * 8;

    char* Wp = (char*)d_ws;   // 128 steps * 16384 B = 2 MB

    hipLaunchKernelGGL(wconv_kernel, dim3(256), dim3(256), 0, stream, Ww, Wn, Wp);
    hipLaunchKernelGGL(router_kernel, dim3(rows / BM), dim3(512), 0, stream,
                       h, bw, bn, nz, Wp, og, oi, of);
}

// Round 10
// 242.871 us; speedup vs baseline: 2.0001x; 1.0281x over previous
//
#include <hip/hip_runtime.h>
#include <hip/hip_bf16.h>
#include <math.h>

// NoisyTopkRouter: rows=32768, D=4096, E=64, k=8.
// R8 (2nd resubmit; two prior infra flakes on a wedged pod — kernel never ran):
// triple-buffered DMA pipeline with counted vmcnt + raw s_barrier (no vmcnt(0)
// drain in the main loop), accM2 dropped (12 MFMA/step). fp16x2 split (main +
// mid@2^11), 512-thread blocks (8 waves, 2x4 grid), W 2-plane image in d_ws.
// Output (fp32): gates[rows*64] | ix[rows*8] | full[rows*64]

typedef __attribute__((ext_vector_type(8))) _Float16 f16x8;
typedef __attribute__((ext_vector_type(4))) float f32x4;
typedef unsigned int u32;

#define BM 64
#define D_DIM 4096
#define NSTEP 128
#define WSTEP_BYTES 16384      // per-step W image: 2 planes x 8KB

// LDS: 3 buffers x (h 8KB + W 16KB) = 72KB
#define BUF_BYTES 24576
#define SMEM_BYTES 73728

__device__ __forceinline__ float softplus_f(float x) {
    return fmaxf(x, 0.0f) + log1pf(expf(-fabsf(x)));
}

__device__ __forceinline__ void gl16(void* lds, const void* g) {
    __builtin_amdgcn_global_load_lds(
        (const __attribute__((address_space(1))) u32*)g,
        (__attribute__((address_space(3))) u32*)lds, 16, 0, 0);
}

#define MFMA16F(A, B, C) __builtin_amdgcn_mfma_f32_16x16x32_f16((A), (B), (C), 0, 0, 0)

// ---- W pre-conversion: 2 fp16 planes (p0 = f16(w), p1 = f16((w-p0)*2048)),
// per-step 16KB fragment-ready image, chunk-swizzled: sc = c4 ^ ((vrow>>2)&3)
__global__ __launch_bounds__(256)
void wconv_kernel(const float* __restrict__ Ww, const float* __restrict__ Wn,
                  char* __restrict__ Wp)
{
    const int bid = blockIdx.x;            // 256 blocks
    const int kc = bid >> 1, half = bid & 1;
    const int t = threadIdx.x;
    const int vrow = half * 64 + (t >> 2); // 0..127 (0-63=Ww, 64-127=Wn)
    const int c4 = t & 3;                  // 16B chunk (8 fp32 k-elements -> 8 fp16)
    const float* src = (vrow < 64) ? (Ww + (size_t)vrow * D_DIM)
                                   : (Wn + (size_t)(vrow - 64) * D_DIM);
    const float4 a = *reinterpret_cast<const float4*>(src + kc * 32 + c4 * 8);
    const float4 b = *reinterpret_cast<const float4*>(src + kc * 32 + c4 * 8 + 4);
    const float f[8] = {a.x, a.y, a.z, a.w, b.x, b.y, b.z, b.w};
    union { _Float16 h[8]; uint4 q; } P0, P1;
#pragma unroll
    for (int i = 0; i < 8; ++i) {
        _Float16 lo = (_Float16)f[i];
        P0.h[i] = lo;
        P1.h[i] = (_Float16)((f[i] - (float)lo) * 2048.0f);
    }
    const int sc = c4 ^ ((vrow >> 2) & 3);
    char* dst = Wp + (size_t)kc * WSTEP_BYTES + vrow * 64 + sc * 16;
    *reinterpret_cast<uint4*>(dst)        = P0.q;
    *reinterpret_cast<uint4*>(dst + 8192) = P1.q;
}

__global__ __launch_bounds__(512, 4)
void router_kernel(const float* __restrict__ h,
                   const float* __restrict__ bw,
                   const float* __restrict__ bn,
                   const float* __restrict__ noise,
                   const char* __restrict__ Wp,
                   float* __restrict__ out_gates,
                   float* __restrict__ out_ix,
                   float* __restrict__ out_full)
{
    __shared__ __align__(16) char smem[SMEM_BYTES];

    const int t    = threadIdx.x;
    const int row0 = blockIdx.x * BM;
    const int lane = t & 63, w = t >> 6;        // 8 waves
    const int c = lane & 15, kg = lane >> 4;
    const int wr = w >> 2, wc = w & 3;          // 2x4 grid: rows wr*32.., vcols wc*32..

    // ---- staging geometry ----
    // h image[row*128 + sc*16] (raw fp32, sc = chunk ^ (row&7)): 1 gl16/thread
    const int hl  = lane >> 3;                  // row-within-8
    const int hsc = (lane & 7) ^ hl;            // pre-swizzled source chunk
    const float* hsrc = h + (size_t)(row0 + w * 8 + hl) * D_DIM + hsc * 4;
    const int hdst = w * 1024;                  // wave-uniform LDS base (+ lane*16 by DMA)
    const char* wsrc = Wp + w * 1024 + lane * 16;

    // ---- accumulators: grp (fold-16 main), sA, accM (@2^11) ----
    f32x4 grp[2][2], sA[2][2], accM[2][2];
#pragma unroll
    for (int fi = 0; fi < 2; ++fi)
#pragma unroll
        for (int j = 0; j < 2; ++j) {
            grp[fi][j] = (f32x4)0.0f; sA[fi][j] = (f32x4)0.0f;
            accM[fi][j] = (f32x4)0.0f;
        }

    // ---- prologue: stage steps 0 and 1 into bufs 0,1 ----
#pragma unroll
    for (int p = 0; p < 2; ++p) {
        char* nb = smem + p * BUF_BYTES;
        gl16(nb + hdst, hsrc + (size_t)p * 32);
        const char* ws = wsrc + (size_t)p * WSTEP_BYTES;
        gl16(nb + 8192 + w * 1024, ws);
        gl16(nb + 16384 + w * 1024, ws + 8192);
    }
    asm volatile("s_waitcnt vmcnt(3)" ::: "memory");   // step-0 loads done
    __builtin_amdgcn_sched_barrier(0);
    __builtin_amdgcn_s_barrier();
    __builtin_amdgcn_sched_barrier(0);

    for (int kc = 0; kc < NSTEP; ++kc) {
        // issue step kc+2 into buf (kc+2)%3 (stays in flight across this step)
        if (kc + 2 < NSTEP) {
            char* nb = smem + ((kc + 2) % 3) * BUF_BYTES;
            gl16(nb + hdst, hsrc + (size_t)(kc + 2) * 32);
            const char* ws = wsrc + (size_t)(kc + 2) * WSTEP_BYTES;
            gl16(nb + 8192 + w * 1024, ws);
            gl16(nb + 16384 + w * 1024, ws + 8192);
        }

        const char* hb = smem + (kc % 3) * BUF_BYTES;
        const char* wb = hb + 8192;

        // ---- A fragments: read raw fp32 h, fp16x2 split in-register ----
        f16x8 A0[2], A1[2];
#pragma unroll
        for (int fi = 0; fi < 2; ++fi) {
            const int arow = wr * 32 + fi * 16 + c;
            const int s0 = ((kg * 2)     ^ (arow & 7)) * 16;
            const int s1 = ((kg * 2 + 1) ^ (arow & 7)) * 16;
            const float4 fa = *reinterpret_cast<const float4*>(hb + arow * 128 + s0);
            const float4 fb = *reinterpret_cast<const float4*>(hb + arow * 128 + s1);
            const float f[8] = {fa.x, fa.y, fa.z, fa.w, fb.x, fb.y, fb.z, fb.w};
#pragma unroll
            for (int i = 0; i < 8; ++i) {
                _Float16 lo = (_Float16)f[i];
                A0[fi][i] = lo;
                A1[fi][i] = (_Float16)((f[i] - (float)lo) * 2048.0f);
            }
        }

        // ---- B fragments + 3-term MFMA ----
#pragma unroll
        for (int j = 0; j < 2; ++j) {
            const int brow = wc * 32 + j * 16 + c;
            const int bo = brow * 64 + ((kg ^ ((brow >> 2) & 3)) * 16);
            const f16x8 B0 = *reinterpret_cast<const f16x8*>(wb + bo);
            const f16x8 B1 = *reinterpret_cast<const f16x8*>(wb + bo + 8192);
#pragma unroll
            for (int fi = 0; fi < 2; ++fi) {
                grp[fi][j]  = MFMA16F(A0[fi], B0, grp[fi][j]);
                accM[fi][j] = MFMA16F(A0[fi], B1, accM[fi][j]);
                accM[fi][j] = MFMA16F(A1[fi], B0, accM[fi][j]);
            }
        }

        // fold group into sA every 16 steps (last fold at kc=127)
        if ((kc & 15) == 15) {
#pragma unroll
            for (int fi = 0; fi < 2; ++fi)
#pragma unroll
                for (int j = 0; j < 2; ++j) {
#pragma unroll
                    for (int e = 0; e < 4; ++e) sA[fi][j][e] += grp[fi][j][e];
                    grp[fi][j] = (f32x4)0.0f;
                }
        }

        // counted wait: step kc+1's loads complete, kc+2's stay in flight
        if (kc + 2 < NSTEP) {
            asm volatile("s_waitcnt vmcnt(3)" ::: "memory");
        } else {
            asm volatile("s_waitcnt vmcnt(0)" ::: "memory");
        }
        __builtin_amdgcn_sched_barrier(0);
        __builtin_amdgcn_s_barrier();
        __builtin_amdgcn_sched_barrier(0);
    }

    // ---- logits -> LDS ----
    // C/D layout: col = lane&15, row = (lane>>4)*4 + reg
    float* lw_s = reinterpret_cast<float*>(smem);            // [64][65]
    float* ln_s = lw_s + 64 * 65;                            // [64][65]
    float* dst = (wc < 2) ? lw_s : ln_s;
#pragma unroll
    for (int fi = 0; fi < 2; ++fi)
#pragma unroll
        for (int j = 0; j < 2; ++j)
#pragma unroll
            for (int r = 0; r < 4; ++r) {
                const int rowl = wr * 32 + fi * 16 + kg * 4 + r;
                const int e = (wc & 1) * 32 + j * 16 + c;
                dst[rowl * 65 + e] = sA[fi][j][r] + accM[fi][j][r] * 4.8828125e-4f; // 2^-11
            }
    __syncthreads();

    // ---- noisy + top-8 + softmaxes: wave w -> rows w*8..w*8+7, lane = expert ----
    const float bwv = bw[lane];
    const float bnv = bn[lane];
    for (int q = 0; q < 8; ++q) {
        const int lrow = w * 8 + q;
        const int grow = row0 + lrow;
        const float lwv = lw_s[lrow * 65 + lane] + bwv;
        const float lnv = ln_s[lrow * 65 + lane] + bnv;
        const float nz  = noise[(size_t)grow * 64 + lane];
        const float v   = lwv + nz * softplus_f(lnv);

        float cur2 = v;
        float m8 = 0.0f;
        int winIdx = 0;
        bool picked = false;
#pragma unroll
        for (int r = 0; r < 8; ++r) {
            float bvv = cur2;
            int   bi  = lane;
#pragma unroll
            for (int off = 32; off; off >>= 1) {
                const float ov = __shfl_xor(bvv, off);
                const int   oi = __shfl_xor(bi, off);
                if (ov > bvv || (ov == bvv && oi < bi)) { bvv = ov; bi = oi; }
            }
            if (r == 0) m8 = bvv;
            if (lane == r) winIdx = bi;
            if (lane == bi) { picked = true; cur2 = -INFINITY; }
        }

        const float pf = expf(v - m8);
        const float pg = picked ? pf : 0.0f;
        float sf = pf, sg = pg;
#pragma unroll
        for (int off = 32; off; off >>= 1) {
            sf += __shfl_xor(sf, off);
            sg += __shfl_xor(sg, off);
        }

        out_full [(size_t)grow * 64 + lane] = pf / sf;
        out_gates[(size_t)grow * 64 + lane] = pg / sg;
        if (lane < 8) out_ix[(size_t)grow * 8 + lane] = (float)winIdx;
    }
}

extern "C" void kernel_launch(void* const* d_in, const int* in_sizes, int n_in,
                              void* d_out, int out_size, void* d_ws, size_t ws_size,
                              hipStream_t stream) {
    const float* h  = (const float*)d_in[0];
    const float* Ww = (const float*)d_in[1];
    const float* bw = (const float*)d_in[2];
    const float* Wn = (const float*)d_in[3];
    const float* bn = (const float*)d_in[4];
    const float* nz = (const float*)d_in[5];

    const int rows = in_sizes[5] / 64;   // 32768

    float* out = (float*)d_out;
    float* og = out;
    float* oi = out + (size_t)rows * 64;
    float* of = out + (size_t)rows * 64 + (size_t)rows * 8;

    char* Wp = (char*)d_ws;   // 128 steps * 16384 B = 2 MB

    hipLaunchKernelGGL(wconv_kernel, dim3(256), dim3(256), 0, stream, Ww, Wn, Wp);
    hipLaunchKernelGGL(router_kernel, dim3(rows / BM), dim3(512), 0, stream,
                       h, bw, bn, nz, Wp, og, oi, of);
}